// Round 5
// baseline (29.928 us; speedup 1.0000x reference)
//
#include <hip/hip_runtime.h>
#include <cmath>

// FilterDelayNetwork: delay(1499) -> 1st-order IIR (pole p≈0.0194) -> tonal FIR.
// Collapsed to a 6-tap FIR since |h_k| decays ×p≈0.0194 per tap; truncation
// error from dropping k>=6 is ~1e-7 (threshold 0.119):
//   z[n] = sum_k h[k] * input[n - 1499 - k]
//   h[0] = b0/(1-beta); h[k] = h[0]*(p-beta)*p^(k-1)
//
// Layout: 8 outputs per thread. Window for outputs [n0, n0+8) is
// x[n0-1504 .. n0-1492]; since 1504 % 8 == 0 and n0 % 8 == 0, the window
// start is 32B-aligned -> exactly 4 aligned 16B loads per 2 16B stores
// (2x read amplification at L1, down from 4x). Output is write-only ->
// nontemporal stores keep it out of L2/L3 so the input stays L3-resident.
//
// NOTE: __builtin_nontemporal_store needs a NATIVE vector type — HIP's
// float4 (HIP_vector_type class) is rejected. Use ext_vector_type(4).

typedef float floatx4 __attribute__((ext_vector_type(4)));

#define NTAPS   6
#define DELAY   1499
#define WIN_OFF 1504   // DELAY + NTAPS - 1 = 1504 (multiple of 8)

struct Taps { float h[NTAPS]; };

__global__ __launch_bounds__(256)
void fdn_fir_kernel(const float* __restrict__ x, float* __restrict__ out,
                    const int n, const Taps taps)
{
    const long long t  = (long long)blockIdx.x * blockDim.x + threadIdx.x;
    const long long n0 = 8 * t;                 // first of 8 output indices
    if (n0 >= n) return;

    const long long base = n0 - WIN_OFF;        // 32B-aligned window start
    float v[16];

    if (base >= 0 && n0 + 8 <= n) {
        // Fast path: 4 aligned 16B loads covering x[base .. base+15].
        const floatx4* p4 = reinterpret_cast<const floatx4*>(x + base);
        floatx4 a = p4[0], b = p4[1], c = p4[2], d = p4[3];
        v[0]=a.x;  v[1]=a.y;  v[2]=a.z;  v[3]=a.w;
        v[4]=b.x;  v[5]=b.y;  v[6]=b.z;  v[7]=b.w;
        v[8]=c.x;  v[9]=c.y;  v[10]=c.z; v[11]=c.w;
        v[12]=d.x; v[13]=d.y; v[14]=d.z; v[15]=d.w;

        float o[8];
        #pragma unroll
        for (int j = 0; j < 8; ++j) {
            float acc = 0.0f;
            #pragma unroll
            for (int k = 0; k < NTAPS; ++k)
                acc = fmaf(taps.h[k], v[j + 5 - k], acc);   // x[n0+j-1499-k]
            o[j] = acc;
        }
        floatx4 s0 = { o[0], o[1], o[2], o[3] };
        floatx4 s1 = { o[4], o[5], o[6], o[7] };
        floatx4* q4 = reinterpret_cast<floatx4*>(out + n0);
        __builtin_nontemporal_store(s0, q4);
        __builtin_nontemporal_store(s1, q4 + 1);
    } else {
        // Slow path: head (implicit zero-pad of the delay line) / tail guard.
        #pragma unroll
        for (int i = 0; i < 16; ++i) {
            long long idx = base + i;
            v[i] = (idx >= 0 && idx < n) ? x[idx] : 0.0f;
        }
        for (int j = 0; j < 8; ++j) {
            long long nn = n0 + j;
            if (nn >= n) break;
            float acc = 0.0f;
            #pragma unroll
            for (int k = 0; k < NTAPS; ++k)
                acc = fmaf(taps.h[k], v[j + 5 - k], acc);
            out[nn] = acc;
        }
    }
}

extern "C" void kernel_launch(void* const* d_in, const int* in_sizes, int n_in,
                              void* d_out, int out_size, void* d_ws, size_t ws_size,
                              hipStream_t stream)
{
    const float* x   = (const float*)d_in[0];
    float*       out = (float*)d_out;
    const int n = in_sizes[0];   // == out_size (2^24)

    // Module constants from the reference (host-side double math, exact).
    const double dd    = 1499.0;                 // DELAYS[0]
    const double t60   = 2.0;
    const double alpha = 0.7;
    const double fs    = 48000.0;

    const double g    = pow(10.0, -3.0 * dd / fs / t60);
    const double p    = log10(10.0 / 4.0) * (1.0 - 1.0 / (alpha * alpha)) * log10(g);
    const double b0   = g * (1.0 - p);
    const double beta = (1.0 - alpha) / (1.0 + alpha);
    const double c    = b0 / (1.0 - beta);

    Taps taps;
    taps.h[0] = (float)c;
    double pk = 1.0;
    for (int k = 1; k < NTAPS; ++k) {
        taps.h[k] = (float)(c * (p - beta) * pk);
        pk *= p;
    }

    const int nThreads = (n + 7) / 8;
    const int block = 256;
    const int grid  = (nThreads + block - 1) / block;
    hipLaunchKernelGGL(fdn_fir_kernel, dim3(grid), dim3(block), 0, stream,
                       x, out, n, taps);
}

// Round 6
// 25.679 us; speedup vs baseline: 1.1655x; 1.1655x over previous
//
#include <hip/hip_runtime.h>
#include <cmath>

// FilterDelayNetwork: delay(1499) -> 1st-order IIR (pole p≈0.0194) -> tonal FIR.
// Collapsed to a 6-tap FIR since |h_k| decays ×p≈0.0194 per tap; truncation
// error from dropping k>=6 is ~1e-7 (threshold 0.119):
//   z[n] = sum_k h[k] * input[n - 1499 - k]
//   h[0] = b0/(1-beta); h[k] = h[0]*(p-beta)*p^(k-1)
//
// Layout: 8 outputs per thread; window start (n0-1504) is 32B-aligned ->
// 4 aligned 16B loads per 2 aligned 16B stores.
// R5 lesson: nontemporal stores REGRESSED (29.9 vs 26.8 µs) — nt bypasses
// L2 write-combining on CDNA, slowing the HBM write path. Plain stores here.

typedef float floatx4 __attribute__((ext_vector_type(4)));

#define NTAPS   6
#define DELAY   1499
#define WIN_OFF 1504   // DELAY + NTAPS - 1 = 1504 (multiple of 8)

struct Taps { float h[NTAPS]; };

__global__ __launch_bounds__(256)
void fdn_fir_kernel(const float* __restrict__ x, float* __restrict__ out,
                    const int n, const Taps taps)
{
    const long long t  = (long long)blockIdx.x * blockDim.x + threadIdx.x;
    const long long n0 = 8 * t;                 // first of 8 output indices
    if (n0 >= n) return;

    const long long base = n0 - WIN_OFF;        // 32B-aligned window start
    float v[16];

    if (base >= 0 && n0 + 8 <= n) {
        // Fast path: 4 aligned 16B loads covering x[base .. base+15].
        const floatx4* p4 = reinterpret_cast<const floatx4*>(x + base);
        floatx4 a = p4[0], b = p4[1], c = p4[2], d = p4[3];
        v[0]=a.x;  v[1]=a.y;  v[2]=a.z;  v[3]=a.w;
        v[4]=b.x;  v[5]=b.y;  v[6]=b.z;  v[7]=b.w;
        v[8]=c.x;  v[9]=c.y;  v[10]=c.z; v[11]=c.w;
        v[12]=d.x; v[13]=d.y; v[14]=d.z; v[15]=d.w;

        float o[8];
        #pragma unroll
        for (int j = 0; j < 8; ++j) {
            float acc = 0.0f;
            #pragma unroll
            for (int k = 0; k < NTAPS; ++k)
                acc = fmaf(taps.h[k], v[j + 5 - k], acc);   // x[n0+j-1499-k]
            o[j] = acc;
        }
        floatx4 s0 = { o[0], o[1], o[2], o[3] };
        floatx4 s1 = { o[4], o[5], o[6], o[7] };
        floatx4* q4 = reinterpret_cast<floatx4*>(out + n0);
        q4[0] = s0;
        q4[1] = s1;
    } else {
        // Slow path: head (implicit zero-pad of the delay line) / tail guard.
        #pragma unroll
        for (int i = 0; i < 16; ++i) {
            long long idx = base + i;
            v[i] = (idx >= 0 && idx < n) ? x[idx] : 0.0f;
        }
        for (int j = 0; j < 8; ++j) {
            long long nn = n0 + j;
            if (nn >= n) break;
            float acc = 0.0f;
            #pragma unroll
            for (int k = 0; k < NTAPS; ++k)
                acc = fmaf(taps.h[k], v[j + 5 - k], acc);
            out[nn] = acc;
        }
    }
}

extern "C" void kernel_launch(void* const* d_in, const int* in_sizes, int n_in,
                              void* d_out, int out_size, void* d_ws, size_t ws_size,
                              hipStream_t stream)
{
    const float* x   = (const float*)d_in[0];
    float*       out = (float*)d_out;
    const int n = in_sizes[0];   // == out_size (2^24)

    // Module constants from the reference (host-side double math, exact).
    const double dd    = 1499.0;                 // DELAYS[0]
    const double t60   = 2.0;
    const double alpha = 0.7;
    const double fs    = 48000.0;

    const double g    = pow(10.0, -3.0 * dd / fs / t60);
    const double p    = log10(10.0 / 4.0) * (1.0 - 1.0 / (alpha * alpha)) * log10(g);
    const double b0   = g * (1.0 - p);
    const double beta = (1.0 - alpha) / (1.0 + alpha);
    const double c    = b0 / (1.0 - beta);

    Taps taps;
    taps.h[0] = (float)c;
    double pk = 1.0;
    for (int k = 1; k < NTAPS; ++k) {
        taps.h[k] = (float)(c * (p - beta) * pk);
        pk *= p;
    }

    const int nThreads = (n + 7) / 8;
    const int block = 256;
    const int grid  = (nThreads + block - 1) / block;
    hipLaunchKernelGGL(fdn_fir_kernel, dim3(grid), dim3(block), 0, stream,
                       x, out, n, taps);
}